// Round 9
// baseline (40.962 us; speedup 1.0000x reference)
//
#include <hip/hip_runtime.h>
#include <math.h>

// out[b, 0:1024]    = -0.5*z^2 - log(std) - 0.5*log(2pi),  z=(x[b,gsc[g]]-mean[g])/std[g]
// out[b, 1024:2048] = cat_logp[c, (int)x[b, csc[c]]]
// B=16384, x:[B,256] f32, NG=NC=1024, K=32.
//
// Design C (R5, best measured) + LDS compression for 8 blocks/CU occupancy:
//  - cat half of x stored as u8 indices (converted once at staging), padded
//    pitch 132B so idx reads spread over 16 banks (raw 128B stride would be
//    a 16-way conflict).
//  - LDS 19,776 B < 20,480 -> 8 blocks/CU (32 waves = full wave slots);
//    R8 measured occupancy sensitivity (6->3 blocks cost 2us), this goes 6->8.
//  - gather-transposed cat phase (lanes=rows, <=8 lines/instr), wave-private
//    transpose tiles, zero cat-phase barriers, 64B-segment flush (R5).
//  - nt stores NOT used (R7: -19%); row-linear mega-flush NOT used (R8: neutral).

#define HALF_LOG_2PI 0.91893853320467274178f

constexpr int BROWS   = 16384;
constexpr int FX      = 256;
constexpr int NG      = 1024;
constexpr int NC      = 1024;
constexpr int KCAT    = 32;
constexpr int OUTW    = NG + NC;   // 2048
constexpr int ROWS_PB = 16;
constexpr int NTHR    = 256;
constexpr int XGP     = 132;       // gauss tile pitch (floats): 528B, 16B-aligned, bank-spread
constexpr int IP      = 132;       // idx tile pitch (bytes): 4-aligned, 16-bank spread
constexpr int CCH     = 128;       // cat cols per chunk (32 per wave)
constexpr int NCHUNK  = NC / CCH;  // 8
constexpr int TPITCH  = 36;        // wave tile pitch: 16B rows, 2-way max

__global__ __launch_bounds__(NTHR, 8) void leaves_kernel(
    const float* __restrict__ x,       // [B, 256]
    const float* __restrict__ gmean,   // [1024]
    const float* __restrict__ gstd,    // [1024]
    const float* __restrict__ clogp,   // [1024, 32]
    const int*   __restrict__ gsc,     // [1024] in [0,128)
    const int*   __restrict__ csc,     // [1024] in [128,256)
    float*       __restrict__ out)     // [B, 2048]
{
    __shared__ float         xg[ROWS_PB * XGP];        // 8448 B: gauss cols f32
    __shared__ unsigned char xi[ROWS_PB * IP];         // 2112 B: cat cols u8 idx
    __shared__ float         wt[4][ROWS_PB * TPITCH];  // 9216 B: wave-private tiles
    // total 19,776 B -> 8 blocks/CU

    const int t = threadIdx.x;
    const long long b0 = (long long)blockIdx.x * ROWS_PB;

    // ---- stage 16 x-rows: thread t handles row t>>4, cols (t&15)*16..+15 ----
    {
        const int r = t >> 4;
        const int q = t & 15;
        const float4* src = (const float4*)(x + (b0 + r) * FX + q * 16);
        if (q < 8) {
            // gaussian cols 0..127: store f32
            float* dst = xg + r * XGP + q * 16;
            #pragma unroll
            for (int k = 0; k < 4; ++k) ((float4*)dst)[k] = src[k];
        } else {
            // cat cols 128..255: convert to u8 idx (values are 0..31 exact)
            const int f0 = q * 16 - 128;
            unsigned int* dst = (unsigned int*)(xi + r * IP + f0);
            #pragma unroll
            for (int k = 0; k < 4; ++k) {
                float4 v = src[k];
                dst[k] = (unsigned int)(int)v.x
                       | ((unsigned int)(int)v.y << 8)
                       | ((unsigned int)(int)v.z << 16)
                       | ((unsigned int)(int)v.w << 24);
            }
        }
    }

    // ---- per-thread gaussian tables (thread owns g-cols 4t..4t+3) ----
    const int4   g4 = ((const int4*)gsc)[t];
    const float4 mu = ((const float4*)gmean)[t];
    const float4 sd = ((const float4*)gstd)[t];
    float4 is, cc4;
    is.x = 1.0f / sd.x;  cc4.x = -logf(sd.x) - HALF_LOG_2PI;
    is.y = 1.0f / sd.y;  cc4.y = -logf(sd.y) - HALF_LOG_2PI;
    is.z = 1.0f / sd.z;  cc4.z = -logf(sd.z) - HALF_LOG_2PI;
    is.w = 1.0f / sd.w;  cc4.w = -logf(sd.w) - HALF_LOG_2PI;

    __syncthreads();   // the ONLY block-wide barrier

    // ---- Gaussian half: 16 rows, coalesced 1KB wave stores ----
    #pragma unroll
    for (int r = 0; r < ROWS_PB; ++r) {
        const float* xr = xg + r * XGP;
        float4 gres;
        { float z = (xr[g4.x] - mu.x) * is.x; gres.x = fmaf(-0.5f * z, z, cc4.x); }
        { float z = (xr[g4.y] - mu.y) * is.y; gres.y = fmaf(-0.5f * z, z, cc4.y); }
        { float z = (xr[g4.z] - mu.z) * is.z; gres.z = fmaf(-0.5f * z, z, cc4.z); }
        { float z = (xr[g4.w] - mu.w) * is.w; gres.w = fmaf(-0.5f * z, z, cc4.w); }
        ((float4*)(out + (b0 + r) * OUTW))[t] = gres;
    }

    // ---- Cat half: fully wave-local, no barriers ----
    const int w    = t >> 6;
    const int l    = t & 63;
    const int grow = l & 15;          // gather mapping: lane's row
    const int gco  = l >> 4;          // 0..3: c sub-offset
    const int frow = l >> 2;          // flush mapping: lane's row
    const int fol  = l & 3;           // 0..3: which 16B of the 64B segment
    float*               tile = wt[w];
    const unsigned char* xip  = xi + grow * IP;

    for (int chunk = 0; chunk < NCHUNK; ++chunk) {
        const int cb = chunk * CCH + w * 32 + gco;   // this thread's c = cb + 4j

        // gather 8 values (32 c's per wave, <=8 lines per wave-instr)
        float v[8];
        #pragma unroll
        for (int j = 0; j < 8; ++j) {
            const int c = cb + j * 4;
            v[j] = clogp[c * KCAT + xip[csc[c] - 128]];
        }

        // in-wave transpose write (2-way max bank overlap)
        #pragma unroll
        for (int j = 0; j < 8; ++j)
            tile[grow * TPITCH + j * 4 + gco] = v[j];

        // read back + store: per store-instr, each of 16 rows gets one 64B segment
        const float* trow = tile + frow * TPITCH;
        float*       drow = out + (b0 + frow) * OUTW + NG + chunk * CCH + w * 32;
        #pragma unroll
        for (int q2 = 0; q2 < 2; ++q2) {
            float4 a = *(const float4*)(trow + q2 * 16 + fol * 4);
            *(float4*)(drow + q2 * 16 + fol * 4) = a;
        }
    }
}

extern "C" void kernel_launch(void* const* d_in, const int* in_sizes, int n_in,
                              void* d_out, int out_size, void* d_ws, size_t ws_size,
                              hipStream_t stream) {
    const float* x     = (const float*)d_in[0];
    const float* gmean = (const float*)d_in[1];
    const float* gstd  = (const float*)d_in[2];
    const float* clogp = (const float*)d_in[3];
    const int*   gsc   = (const int*)d_in[4];
    const int*   csc   = (const int*)d_in[5];
    float*       out   = (float*)d_out;

    leaves_kernel<<<dim3(BROWS / ROWS_PB), dim3(NTHR), 0, stream>>>(
        x, gmean, gstd, clogp, gsc, csc, out);
}

// Round 11
// 30.522 us; speedup vs baseline: 1.3420x; 1.3420x over previous
//
#include <hip/hip_runtime.h>
#include <math.h>

// out[b, 0:1024]    = -0.5*z^2 - log(std) - 0.5*log(2pi),  z=(x[b,gsc[g]]-mean[g])/std[g]
// out[b, 1024:2048] = cat_logp[c, (int)x[b, csc[c]]]
// B=16384, x:[B,256] f32, NG=NC=1024, K=32.
//
// FINAL (revert to R3, best validated: 30.54us = ~4.95 TB/s mixed, 79% of
// the 6.29 TB/s copy ceiling). Session evidence that this is the plateau:
//   R4 pipelined dbuf 31.3 | R5 barrier-free 30.8 | R7 nt stores 36.3 |
//   R8 row-linear flush 32.7 | R9 launch_bounds(,8) 41.0 | R10 split 47/fail.
// Key structure (R3): gather-transposed cat half — within a wave, lanes=rows
// (l&15), c-offset=l>>4, so one gather instr touches 4 consecutive c's x 128B
// table blocks (<=8 cache lines/instr vs 64 naive). Cat results transit a
// padded LDS tile; both halves store coalesced. 33KB LDS -> 4-6 blocks/CU.

#define HALF_LOG_2PI 0.91893853320467274178f

constexpr int BROWS   = 16384;
constexpr int FX      = 256;
constexpr int NG      = 1024;
constexpr int NC      = 1024;
constexpr int KCAT    = 32;
constexpr int OUTW    = NG + NC;   // 2048
constexpr int ROWS_PB = 16;
constexpr int NTHR    = 256;
constexpr int XPITCH  = FX + 1;    // 257: idx-read bank = (row + col) % 32 -> spread
constexpr int CCH     = 128;       // cat cols per chunk
constexpr int NCHUNK  = NC / CCH;  // 8
constexpr int CPITCH  = CCH + 4;   // 132: tile bank = (4*row + off) % 32 -> 2-way max

__global__ __launch_bounds__(NTHR) void leaves_kernel(
    const float* __restrict__ x,       // [B, 256]
    const float* __restrict__ gmean,   // [1024]
    const float* __restrict__ gstd,    // [1024]
    const float* __restrict__ clogp,   // [1024, 32]
    const int*   __restrict__ gsc,     // [1024] in [0,128)
    const int*   __restrict__ csc,     // [1024] in [128,256)
    float*       __restrict__ out)     // [B, 2048]
{
    __shared__ float xs[ROWS_PB * XPITCH];   // 16448 B
    __shared__ float cts[ROWS_PB * CPITCH];  //  8448 B

    const int t = threadIdx.x;
    const long long b0 = (long long)blockIdx.x * ROWS_PB;

    // ---- stage 16 x-rows: thread t loads row t>>4, cols (t&15)*16..+15 ----
    {
        const int r  = t >> 4;
        const int c0 = (t & 15) * 16;
        const float* src = x + (b0 + r) * FX + c0;
        float*       dst = xs + r * XPITCH + c0;
        #pragma unroll
        for (int q = 0; q < 4; ++q) {
            float4 v = ((const float4*)src)[q];
            dst[q * 4 + 0] = v.x; dst[q * 4 + 1] = v.y;
            dst[q * 4 + 2] = v.z; dst[q * 4 + 3] = v.w;
        }
    }

    // ---- per-thread gaussian tables (thread owns g-cols 4t..4t+3) ----
    const int4   g4 = ((const int4*)gsc)[t];
    const float4 mu = ((const float4*)gmean)[t];
    const float4 sd = ((const float4*)gstd)[t];
    float4 is, cc;
    is.x = 1.0f / sd.x;  cc.x = -logf(sd.x) - HALF_LOG_2PI;
    is.y = 1.0f / sd.y;  cc.y = -logf(sd.y) - HALF_LOG_2PI;
    is.z = 1.0f / sd.z;  cc.z = -logf(sd.z) - HALF_LOG_2PI;
    is.w = 1.0f / sd.w;  cc.w = -logf(sd.w) - HALF_LOG_2PI;

    __syncthreads();

    // ---- Gaussian half: 16 rows, coalesced 1KB wave stores ----
    #pragma unroll
    for (int r = 0; r < ROWS_PB; ++r) {
        const float* xr = xs + r * XPITCH;
        float4 gres;
        { float z = (xr[g4.x] - mu.x) * is.x; gres.x = fmaf(-0.5f * z, z, cc.x); }
        { float z = (xr[g4.y] - mu.y) * is.y; gres.y = fmaf(-0.5f * z, z, cc.y); }
        { float z = (xr[g4.z] - mu.z) * is.z; gres.z = fmaf(-0.5f * z, z, cc.z); }
        { float z = (xr[g4.w] - mu.w) * is.w; gres.w = fmaf(-0.5f * z, z, cc.w); }
        ((float4*)(out + (b0 + r) * OUTW))[t] = gres;
    }

    // ---- Cat half: lanes = rows; 4 consecutive c per wave-instr ----
    const int w   = t >> 6;        // wave 0..3
    const int l   = t & 63;
    const int row = l & 15;        // lane's row
    const int co  = l >> 4;        // 0..3: c sub-offset
    const float* xrp = xs + row * XPITCH;

    const int wr = t >> 4;          // write-phase row
    const int wo = (t & 15) * 4;    // write-phase col offset

    for (int chunk = 0; chunk < NCHUNK; ++chunk) {
        const int cb = chunk * CCH + w * 32 + co;   // this thread's c = cb + 4j

        int sc[8];
        #pragma unroll
        for (int j = 0; j < 8; ++j) sc[j] = csc[cb + j * 4];

        int ix[8];
        #pragma unroll
        for (int j = 0; j < 8; ++j) ix[j] = (int)xrp[sc[j]];

        float v[8];
        #pragma unroll
        for (int j = 0; j < 8; ++j) v[j] = clogp[(cb + j * 4) * KCAT + ix[j]];

        #pragma unroll
        for (int j = 0; j < 8; ++j)
            cts[row * CPITCH + w * 32 + j * 4 + co] = v[j];

        __syncthreads();

        // flush: thread t writes row wr, floats wo..wo+3 and wo+64..wo+67
        {
            float4 a = *(const float4*)(cts + wr * CPITCH + wo);
            float4 b = *(const float4*)(cts + wr * CPITCH + wo + 64);
            float* dst = out + (b0 + wr) * OUTW + NG + chunk * CCH;
            *(float4*)(dst + wo)      = a;
            *(float4*)(dst + wo + 64) = b;
        }
        __syncthreads();
    }
}

extern "C" void kernel_launch(void* const* d_in, const int* in_sizes, int n_in,
                              void* d_out, int out_size, void* d_ws, size_t ws_size,
                              hipStream_t stream) {
    const float* x     = (const float*)d_in[0];
    const float* gmean = (const float*)d_in[1];
    const float* gstd  = (const float*)d_in[2];
    const float* clogp = (const float*)d_in[3];
    const int*   gsc   = (const int*)d_in[4];
    const int*   csc   = (const int*)d_in[5];
    float*       out   = (float*)d_out;

    leaves_kernel<<<dim3(BROWS / ROWS_PB), dim3(NTHR), 0, stream>>>(
        x, gmean, gstd, clogp, gsc, csc, out);
}